// Round 1
// baseline (226.437 us; speedup 1.0000x reference)
//
#include <hip/hip_runtime.h>
#include <hip/hip_bf16.h>
#include <math.h>

#define N_NODES 3072
#define DIM     256
#define NH      8
#define HD      32
#define E_EDGES 98304
#define B_GRAPHS 16
#define MAXC    388     // padded LDS stride for score tile (mod 32 == 4 -> <=2-way bank conflicts)
#define TR      32      // rows per attention tile
#define SCALE   0.17677669529663689f   // 1/sqrt(32)

// ---------------- utility ----------------
__global__ void zero_ints(int* __restrict__ a, int n) {
    int i = blockIdx.x * blockDim.x + threadIdx.x;
    if (i < n) a[i] = 0;
}

// ---------------- fused QKV projection ----------------
// grid 384, block 256. 8 rows per block.
__global__ __launch_bounds__(256) void qkv_proj(
    const float* __restrict__ x,
    const float* __restrict__ Wq, const float* __restrict__ bq,
    const float* __restrict__ Wk, const float* __restrict__ bk,
    const float* __restrict__ Wv, const float* __restrict__ bv,
    float* __restrict__ Q, float* __restrict__ K, float* __restrict__ V)
{
    __shared__ float xs[8][DIM];
    const int row0 = blockIdx.x * 8;
    const int t = threadIdx.x;
    for (int i = t; i < 8 * DIM; i += 256) xs[i >> 8][i & 255] = x[(size_t)row0 * DIM + i];
    __syncthreads();

    float accQ[8] = {0,0,0,0,0,0,0,0};
    float accK[8] = {0,0,0,0,0,0,0,0};
    float accV[8] = {0,0,0,0,0,0,0,0};
    const int j = t;
    #pragma unroll 4
    for (int k = 0; k < DIM; ++k) {
        float wq = Wq[k * DIM + j];
        float wk = Wk[k * DIM + j];
        float wv = Wv[k * DIM + j];
        #pragma unroll
        for (int r = 0; r < 8; ++r) {
            float xv = xs[r][k];
            accQ[r] = fmaf(xv, wq, accQ[r]);
            accK[r] = fmaf(xv, wk, accK[r]);
            accV[r] = fmaf(xv, wv, accV[r]);
        }
    }
    float bqv = bq[j], bkv = bk[j], bvv = bv[j];
    #pragma unroll
    for (int r = 0; r < 8; ++r) {
        size_t o = (size_t)(row0 + r) * DIM + j;
        Q[o] = accQ[r] + bqv;
        K[o] = accK[r] + bkv;
        V[o] = accV[r] + bvv;
    }
}

// ---------------- edge CSR build ----------------
__global__ void edge_count(const int* __restrict__ erow, int* __restrict__ counts) {
    int e = blockIdx.x * blockDim.x + threadIdx.x;
    if (e < E_EDGES) atomicAdd(&counts[erow[e]], 1);
}

// single block, 1024 threads, N=3072=3*1024
__global__ __launch_bounds__(1024) void scan_rows(const int* __restrict__ counts,
                                                  int* __restrict__ rowstart) {
    __shared__ int lds[1024];
    const int t = threadIdx.x;
    int c0 = counts[3 * t], c1 = counts[3 * t + 1], c2 = counts[3 * t + 2];
    int local = c0 + c1 + c2;
    lds[t] = local;
    __syncthreads();
    for (int off = 1; off < 1024; off <<= 1) {
        int v = (t >= off) ? lds[t - off] : 0;
        __syncthreads();
        lds[t] += v;
        __syncthreads();
    }
    int incl = lds[t];
    int base = incl - local;
    rowstart[3 * t]     = base;
    rowstart[3 * t + 1] = base + c0;
    rowstart[3 * t + 2] = base + c0 + c1;
    if (t == 1023) rowstart[N_NODES] = incl;
}

__global__ void edge_fill(const int* __restrict__ erow, const int* __restrict__ ecolin,
                          const float* __restrict__ ea, const float* __restrict__ We,
                          const float* __restrict__ be,
                          const int* __restrict__ rowstart, int* __restrict__ cursor,
                          int* __restrict__ ecol, float* __restrict__ ebias) {
    int e = blockIdx.x * blockDim.x + threadIdx.x;
    if (e >= E_EDGES) return;
    int row = erow[e];
    int pos = rowstart[row] + atomicAdd(&cursor[row], 1);
    ecol[pos] = ecolin[e];
    float a0 = ea[e * 4 + 0], a1 = ea[e * 4 + 1], a2 = ea[e * 4 + 2], a3 = ea[e * 4 + 3];
    #pragma unroll
    for (int h = 0; h < NH; ++h) {
        float b = fmaf(a0, We[0 * NH + h],
                  fmaf(a1, We[1 * NH + h],
                  fmaf(a2, We[2 * NH + h],
                  fmaf(a3, We[3 * NH + h], be[h]))));
        ebias[(size_t)pos * NH + h] = b;
    }
}

// ---------------- graph ranges from sorted batch ----------------
__global__ void graph_ranges(const int* __restrict__ batch, int* __restrict__ gstart) {
    int i = blockIdx.x * blockDim.x + threadIdx.x;
    if (i >= N_NODES) return;
    int b  = batch[i];
    int bp = (i == 0) ? -1 : batch[i - 1];
    for (int g = bp + 1; g <= b; ++g) gstart[g] = i;
    if (i == N_NODES - 1)
        for (int g = b + 1; g <= B_GRAPHS; ++g) gstart[g] = N_NODES;
}

// ---------------- fused block-diagonal attention ----------------
// grid (16 graphs, 12 tiles, 8 heads), block 256
__global__ __launch_bounds__(256) void attn(
    const float* __restrict__ Q, const float* __restrict__ K, const float* __restrict__ V,
    const int* __restrict__ gstart, const int* __restrict__ rowstart,
    const int* __restrict__ ecol, const float* __restrict__ ebias,
    float* __restrict__ pre)
{
    __shared__ float s[TR][MAXC];
    __shared__ float qsh[TR][HD];
    __shared__ float rowinv[TR];
    __shared__ int   rs_sh[TR + 1];

    const int g = blockIdx.x, tile = blockIdx.y, h = blockIdx.z;
    const int gs = gstart[g], ge = gstart[g + 1];
    const int row0 = gs + tile * TR;
    if (row0 >= ge) return;
    const int nrows = min(TR, ge - row0);
    const int ncols = ge - gs;          // within-graph column count (all valid, no mask needed)
    const int t = threadIdx.x;

    // stage Q tile + CSR offsets
    for (int i = t; i < nrows * HD; i += 256) {
        int r = i >> 5, c = i & 31;
        qsh[r][c] = Q[(size_t)(row0 + r) * DIM + h * HD + c];
    }
    if (t <= nrows) rs_sh[t] = rowstart[row0 + t];
    __syncthreads();

    // ---- QK^T: one column per thread, K in regs, Q broadcast from LDS ----
    for (int c = t; c < ncols; c += 256) {
        const float4* kp = (const float4*)(K + (size_t)(gs + c) * DIM + h * HD);
        float4 kv[8];
        #pragma unroll
        for (int q = 0; q < 8; ++q) kv[q] = kp[q];
        for (int r = 0; r < nrows; ++r) {
            const float4* qp = (const float4*)qsh[r];
            float d0 = 0.f, d1 = 0.f, d2 = 0.f, d3 = 0.f;
            #pragma unroll
            for (int q = 0; q < 8; ++q) {
                float4 qv = qp[q];
                d0 = fmaf(qv.x, kv[q].x, d0);
                d1 = fmaf(qv.y, kv[q].y, d1);
                d2 = fmaf(qv.z, kv[q].z, d2);
                d3 = fmaf(qv.w, kv[q].w, d3);
            }
            s[r][c] = ((d0 + d1) + (d2 + d3)) * SCALE;
        }
    }
    __syncthreads();

    // ---- edge bias scatter (duplicates accumulate via LDS atomics) ----
    {
        int e0 = rs_sh[0], e1 = rs_sh[nrows];
        for (int idx = e0 + t; idx < e1; idx += 256) {
            int lo = 0, hi = nrows;          // find row: rs_sh[lo] <= idx < rs_sh[lo+1]
            while (hi - lo > 1) {
                int mid = (lo + hi) >> 1;
                if (rs_sh[mid] <= idx) lo = mid; else hi = mid;
            }
            int col = ecol[idx] - gs;
            if (col >= 0 && col < ncols)     // cross-graph edges are masked anyway -> skip
                atomicAdd(&s[lo][col], ebias[(size_t)idx * NH + h]);
        }
    }
    __syncthreads();

    // ---- per-row softmax: 8 lanes per row, store unnormalized exp ----
    {
        int r = t >> 3, sub = t & 7;
        if (r < nrows) {
            float m = -INFINITY;
            for (int c = sub; c < ncols; c += 8) m = fmaxf(m, s[r][c]);
            m = fmaxf(m, __shfl_xor(m, 1, 8));
            m = fmaxf(m, __shfl_xor(m, 2, 8));
            m = fmaxf(m, __shfl_xor(m, 4, 8));
            float sum = 0.f;
            for (int c = sub; c < ncols; c += 8) {
                float e = __expf(s[r][c] - m);
                s[r][c] = e;
                sum += e;
            }
            sum += __shfl_xor(sum, 1, 8);
            sum += __shfl_xor(sum, 2, 8);
            sum += __shfl_xor(sum, 4, 8);
            if (sub == 0) rowinv[r] = 1.0f / sum;
        }
    }
    __syncthreads();

    // ---- PV: thread = (rowgroup, k); V load shared across 4 rows ----
    {
        const int k = t & 31, rg = t >> 5;
        float a0 = 0.f, a1 = 0.f, a2 = 0.f, a3 = 0.f;
        const float* vbase = V + (size_t)gs * DIM + h * HD + k;
        #pragma unroll 4
        for (int c = 0; c < ncols; ++c) {
            float v = vbase[(size_t)c * DIM];
            a0 = fmaf(s[rg][c],      v, a0);
            a1 = fmaf(s[rg + 8][c],  v, a1);
            a2 = fmaf(s[rg + 16][c], v, a2);
            a3 = fmaf(s[rg + 24][c], v, a3);
        }
        if (rg      < nrows) pre[(size_t)(row0 + rg)      * DIM + h * HD + k] = a0 * rowinv[rg];
        if (rg + 8  < nrows) pre[(size_t)(row0 + rg + 8)  * DIM + h * HD + k] = a1 * rowinv[rg + 8];
        if (rg + 16 < nrows) pre[(size_t)(row0 + rg + 16) * DIM + h * HD + k] = a2 * rowinv[rg + 16];
        if (rg + 24 < nrows) pre[(size_t)(row0 + rg + 24) * DIM + h * HD + k] = a3 * rowinv[rg + 24];
    }
}

// ---------------- output projection ----------------
__global__ __launch_bounds__(256) void out_proj(
    const float* __restrict__ pre, const float* __restrict__ Wo,
    const float* __restrict__ bo, float* __restrict__ out)
{
    __shared__ float xs[8][DIM];
    const int row0 = blockIdx.x * 8;
    const int t = threadIdx.x;
    for (int i = t; i < 8 * DIM; i += 256) xs[i >> 8][i & 255] = pre[(size_t)row0 * DIM + i];
    __syncthreads();

    float acc[8] = {0,0,0,0,0,0,0,0};
    #pragma unroll 4
    for (int k = 0; k < DIM; ++k) {
        float w = Wo[k * DIM + t];
        #pragma unroll
        for (int r = 0; r < 8; ++r) acc[r] = fmaf(xs[r][k], w, acc[r]);
    }
    float b = bo[t];
    #pragma unroll
    for (int r = 0; r < 8; ++r) out[(size_t)(row0 + r) * DIM + t] = acc[r] + b;
}

// ---------------- launch ----------------
extern "C" void kernel_launch(void* const* d_in, const int* in_sizes, int n_in,
                              void* d_out, int out_size, void* d_ws, size_t ws_size,
                              hipStream_t stream) {
    const float* x   = (const float*)d_in[0];
    const float* ea  = (const float*)d_in[1];
    const float* Wq  = (const float*)d_in[2];  const float* bq = (const float*)d_in[3];
    const float* Wk  = (const float*)d_in[4];  const float* bk = (const float*)d_in[5];
    const float* Wv  = (const float*)d_in[6];  const float* bv = (const float*)d_in[7];
    const float* Wo  = (const float*)d_in[8];  const float* bo = (const float*)d_in[9];
    const float* We  = (const float*)d_in[10]; const float* be = (const float*)d_in[11];
    const int*   eidx  = (const int*)d_in[12];
    const int*   batch = (const int*)d_in[13];
    const int* erow   = eidx;
    const int* ecolin = eidx + E_EDGES;

    // workspace layout
    float* Q   = (float*)d_ws;
    float* K   = Q + (size_t)N_NODES * DIM;
    float* V   = K + (size_t)N_NODES * DIM;
    float* pre = V + (size_t)N_NODES * DIM;
    int* counts   = (int*)(pre + (size_t)N_NODES * DIM);
    int* cursor   = counts + N_NODES;        // adjacent to counts for joint zeroing
    int* rowstart = cursor + N_NODES;        // N+1
    int* gstart   = rowstart + (N_NODES + 1);// B+1
    int* ecol     = gstart + (B_GRAPHS + 1);
    float* ebias  = (float*)(ecol + E_EDGES);

    zero_ints<<<dim3((2 * N_NODES + 255) / 256), dim3(256), 0, stream>>>(counts, 2 * N_NODES);
    qkv_proj<<<dim3(N_NODES / 8), dim3(256), 0, stream>>>(x, Wq, bq, Wk, bk, Wv, bv, Q, K, V);
    edge_count<<<dim3(E_EDGES / 256), dim3(256), 0, stream>>>(erow, counts);
    scan_rows<<<dim3(1), dim3(1024), 0, stream>>>(counts, rowstart);
    edge_fill<<<dim3(E_EDGES / 256), dim3(256), 0, stream>>>(erow, ecolin, ea, We, be,
                                                             rowstart, cursor, ecol, ebias);
    graph_ranges<<<dim3(N_NODES / 256), dim3(256), 0, stream>>>(batch, gstart);
    attn<<<dim3(B_GRAPHS, 12, NH), dim3(256), 0, stream>>>(Q, K, V, gstart, rowstart,
                                                           ecol, ebias, pre);
    out_proj<<<dim3(N_NODES / 8), dim3(256), 0, stream>>>(pre, Wo, bo, (float*)d_out);
}